// Round 4
// baseline (726.285 us; speedup 1.0000x reference)
//
#include <hip/hip_runtime.h>
#include <stdint.h>

typedef short bf16x8 __attribute__((ext_vector_type(8)));
typedef float f32x4  __attribute__((ext_vector_type(4)));

constexpr int BT = 4096;   // tokens
constexpr int DD = 1024;   // model dim
constexpr int OO = 1024;   // output dim
constexpr int EE = 8;      // experts
constexpr int HH = 4096;   // hidden dim
constexpr int SLOTS = 2 * BT;  // 8192

__device__ __forceinline__ unsigned short f2bf(float f) {
  unsigned u = __float_as_uint(f);
  u += 0x7fffu + ((u >> 16) & 1u);   // round-to-nearest-even
  return (unsigned short)(u >> 16);
}

// async 16B global->LDS. LDS dest is wave-uniform base; HW adds lane*16.
__device__ __forceinline__ void glds16(const unsigned short* g, unsigned short* l) {
  __builtin_amdgcn_global_load_lds(
      (const __attribute__((address_space(1))) void*)g,
      (__attribute__((address_space(3))) void*)l, 16, 0, 0);
}

// ---------- router: logits, top-2 softmax, expert lists; also x -> bf16 ----------
__global__ __launch_bounds__(256) void router_k(const float* __restrict__ x,
                                                const float* __restrict__ gw,
                                                const float* __restrict__ gb,
                                                unsigned short* __restrict__ xb,
                                                int* __restrict__ cnt,
                                                int* __restrict__ list,
                                                float* __restrict__ rw) {
  int wave = threadIdx.x >> 6, lane = threadIdx.x & 63;
  int b = blockIdx.x * 4 + wave;
  const float* xrow = x + (size_t)b * DD;
  float acc[8];
#pragma unroll
  for (int e = 0; e < 8; ++e) acc[e] = 0.f;
#pragma unroll
  for (int i = 0; i < 4; ++i) {
    int d0 = i * 256 + lane * 4;
    float4 v = *(const float4*)&xrow[d0];
    unsigned lo = (unsigned)f2bf(v.x) | ((unsigned)f2bf(v.y) << 16);
    unsigned hi = (unsigned)f2bf(v.z) | ((unsigned)f2bf(v.w) << 16);
    *(uint2*)&xb[(size_t)b * DD + d0] = make_uint2(lo, hi);
    const float* g0 = &gw[(size_t)d0 * 8];
    float fv[4] = {v.x, v.y, v.z, v.w};
#pragma unroll
    for (int q = 0; q < 4; ++q) {
      float4 ga = *(const float4*)&g0[q * 8];
      float4 gc = *(const float4*)&g0[q * 8 + 4];
      acc[0] += fv[q] * ga.x; acc[1] += fv[q] * ga.y;
      acc[2] += fv[q] * ga.z; acc[3] += fv[q] * ga.w;
      acc[4] += fv[q] * gc.x; acc[5] += fv[q] * gc.y;
      acc[6] += fv[q] * gc.z; acc[7] += fv[q] * gc.w;
    }
  }
#pragma unroll
  for (int off = 32; off > 0; off >>= 1) {
#pragma unroll
    for (int e = 0; e < 8; ++e) acc[e] += __shfl_down(acc[e], off);
  }
  if (lane == 0) {
    float v[8];
#pragma unroll
    for (int e = 0; e < 8; ++e) v[e] = acc[e] + gb[e];
    int i0 = 0;
#pragma unroll
    for (int e = 1; e < 8; ++e) if (v[e] > v[i0]) i0 = e;
    int i1 = (i0 == 0) ? 1 : 0;
#pragma unroll
    for (int e = 0; e < 8; ++e) if (e != i0 && v[e] > v[i1]) i1 = e;
    float e1 = __expf(v[i1] - v[i0]);
    float inv = 1.0f / (1.0f + e1);
    int p0 = atomicAdd(&cnt[i0], 1);
    list[i0 * BT + p0] = 2 * b;     rw[2 * b]     = inv;
    int p1 = atomicAdd(&cnt[i1], 1);
    list[i1 * BT + p1] = 2 * b + 1; rw[2 * b + 1] = e1 * inv;
  }
}

// ---- tile maps: 128-row tiles (gemm1) and 256-row tiles (gemm2) ----
__global__ void tilemap_k(const int* __restrict__ cnt,
                          int* __restrict__ tA, int* __restrict__ ntA,
                          int* __restrict__ tB, int* __restrict__ ntB) {
  if (threadIdx.x == 0 && blockIdx.x == 0) {
    int a = 0, b = 0, basewalk = 0;
    for (int e = 0; e < EE; ++e) {
      int c = cnt[e];
      for (int m0 = 0; m0 < c; m0 += 128) {
        tA[4 * a] = e; tA[4 * a + 1] = m0; tA[4 * a + 2] = basewalk + m0; ++a;
      }
      for (int m0 = 0; m0 < c; m0 += 256) {
        tB[4 * b] = e; tB[4 * b + 1] = m0; tB[4 * b + 2] = basewalk + m0; ++b;
      }
      basewalk += c;
    }
    *ntA = a;
    *ntB = b;
  }
}

// ------- transpose+convert: src fp32 [E][R][C] -> dst bf16 [E][C][R] -------
__global__ __launch_bounds__(256) void cvt_t_k(const float* __restrict__ src,
                                               unsigned short* __restrict__ dst,
                                               int R, int C) {
  __shared__ unsigned short tile[64][66];
  int e = blockIdx.z;
  const float* s = src + (size_t)e * R * C;
  unsigned short* d = dst + (size_t)e * R * C;
  int r0 = blockIdx.x << 6, c0 = blockIdx.y << 6;
  int t = threadIdx.x;
#pragma unroll
  for (int p = 0; p < 4; ++p) {
    int ch = p * 256 + t;
    int rr = ch >> 4, cc = (ch & 15) << 2;
    float4 v = *(const float4*)&s[(size_t)(r0 + rr) * C + c0 + cc];
    unsigned lo = (unsigned)f2bf(v.x) | ((unsigned)f2bf(v.y) << 16);
    unsigned hi = (unsigned)f2bf(v.z) | ((unsigned)f2bf(v.w) << 16);
    *(uint2*)&tile[rr][cc] = make_uint2(lo, hi);
  }
  __syncthreads();
#pragma unroll
  for (int p = 0; p < 4; ++p) {
    int ch = p * 256 + t;
    int cc = ch >> 4, rr = (ch & 15) << 2;
    unsigned short v0 = tile[rr + 0][cc];
    unsigned short v1 = tile[rr + 1][cc];
    unsigned short v2 = tile[rr + 2][cc];
    unsigned short v3 = tile[rr + 3][cc];
    unsigned lo = (unsigned)v0 | ((unsigned)v1 << 16);
    unsigned hi = (unsigned)v2 | ((unsigned)v3 << 16);
    *(uint2*)&d[(size_t)(c0 + cc) * R + r0 + rr] = make_uint2(lo, hi);
  }
}

// ----- GEMM1: hc[base+row] = relu(x[tok] @ w1[e] + b1[e]), compacted layout -----
// grid: (HH/128, 72). 128x128 tile, 4 waves. LDS-staged coalesced epilogue.
__global__ __launch_bounds__(256, 4) void gemm1_k(const unsigned short* __restrict__ xb,
                                                  const unsigned short* __restrict__ w1t,
                                                  const float* __restrict__ b1,
                                                  const int* __restrict__ cnt,
                                                  const int* __restrict__ list,
                                                  const int* __restrict__ tmap,
                                                  const int* __restrict__ ntiles,
                                                  unsigned short* __restrict__ hc) {
  int ti = blockIdx.y;
  if (ti >= *ntiles) return;
  int e = tmap[4 * ti], m0 = tmap[4 * ti + 1], base = tmap[4 * ti + 2];
  int cnt_e = cnt[e];
  int n0 = blockIdx.x * 128;

  __shared__ int slotbuf[128];
  // smem: during K-loop  = Ash[128*64] | Bsh[128*64]  (32 KB)
  //       during epilogue = epi[128][136]             (34.8 KB)
  __shared__ __align__(16) unsigned short smem[128 * 136];
  unsigned short* Ash = smem;
  unsigned short* Bsh = smem + 128 * 64;

  int t = threadIdx.x;
  if (t < 128) {
    int r = m0 + t;
    slotbuf[t] = list[e * BT + (r < cnt_e ? r : 0)];
  }
  __syncthreads();

  int w = t >> 6, l = t & 63;
  int lm = l & 15, lq = l >> 4;
  int wm = (w & 1) * 64, wn = (w >> 1) * 64;

  const unsigned short* Bsrc = w1t + (size_t)e * HH * DD + (size_t)n0 * DD;

  const unsigned short* aS[4];
  const unsigned short* bS[4];
  unsigned short* aL[4];
  unsigned short* bL[4];
#pragma unroll
  for (int j = 0; j < 4; ++j) {
    int idx = 4 * w + j;
    int row = idx * 8 + (l >> 3);
    int koff = (l & 7) * 8;
    int tok = slotbuf[row] >> 1;
    aS[j] = xb + (size_t)tok * DD + koff;
    bS[j] = Bsrc + (size_t)row * DD + koff;
    aL[j] = &Ash[idx * 512];
    bL[j] = &Bsh[idx * 512];
  }

  f32x4 acc[4][4];
#pragma unroll
  for (int mi = 0; mi < 4; ++mi)
#pragma unroll
    for (int ni = 0; ni < 4; ++ni) acc[mi][ni] = f32x4{0.f, 0.f, 0.f, 0.f};

  for (int k0 = 0; k0 < DD; k0 += 64) {
#pragma unroll
    for (int j = 0; j < 4; ++j) glds16(aS[j] + k0, aL[j]);
#pragma unroll
    for (int j = 0; j < 4; ++j) glds16(bS[j] + k0, bL[j]);
    __syncthreads();
#pragma unroll
    for (int ks = 0; ks < 2; ++ks) {
      bf16x8 af[4], bfr[4];
      int kb = ks * 32 + lq * 8;
#pragma unroll
      for (int mi = 0; mi < 4; ++mi)
        af[mi] = *(const bf16x8*)&Ash[(wm + mi * 16 + lm) * 64 + kb];
#pragma unroll
      for (int ni = 0; ni < 4; ++ni)
        bfr[ni] = *(const bf16x8*)&Bsh[(wn + ni * 16 + lm) * 64 + kb];
#pragma unroll
      for (int mi = 0; mi < 4; ++mi)
#pragma unroll
        for (int ni = 0; ni < 4; ++ni)
          acc[mi][ni] = __builtin_amdgcn_mfma_f32_16x16x32_bf16(af[mi], bfr[ni], acc[mi][ni], 0, 0, 0);
    }
    __syncthreads();
  }

  // ---- epilogue: acc -> LDS (bf16, padded rows) -> coalesced global writes ----
#pragma unroll
  for (int ni = 0; ni < 4; ++ni) {
    int col = wn + ni * 16 + lm;
    float bias = b1[e * HH + n0 + col];
#pragma unroll
    for (int mi = 0; mi < 4; ++mi) {
      int rbase = wm + mi * 16 + lq * 4;
#pragma unroll
      for (int r = 0; r < 4; ++r)
        smem[(rbase + r) * 136 + col] = f2bf(fmaxf(acc[mi][ni][r] + bias, 0.0f));
    }
  }
  __syncthreads();
  int rr = t >> 4, cl = (t & 15) * 8;
#pragma unroll
  for (int p = 0; p < 8; ++p) {
    int row = p * 16 + rr;
    if (m0 + row < cnt_e) {
      bf16x8 v = *(const bf16x8*)&smem[row * 136 + cl];
      *(bf16x8*)&hc[(size_t)(base + row) * HH + n0 + cl] = v;
    }
  }
}

// -- GEMM2: y[z][slot] = rw*(hc_rows @ w2[e] + b2[e] [z==0]) ; or atomic into out --
// grid: (OO/128, 40, zsplit). 256x128 tile, 8 waves (512 thr), 2 blocks/CU.
__global__ __launch_bounds__(512, 4) void gemm2_k(const unsigned short* __restrict__ hc,
                                                  const unsigned short* __restrict__ w2t,
                                                  const float* __restrict__ b2,
                                                  const int* __restrict__ cnt,
                                                  const int* __restrict__ list,
                                                  const int* __restrict__ tmap,
                                                  const int* __restrict__ ntiles,
                                                  const float* __restrict__ rw,
                                                  float* __restrict__ ybuf,
                                                  float* __restrict__ out) {
  int ti = blockIdx.y;
  if (ti >= *ntiles) return;
  int e = tmap[4 * ti], m0 = tmap[4 * ti + 1], base = tmap[4 * ti + 2];
  int cnt_e = cnt[e];
  int n0 = blockIdx.x * 128;
  int ksl = HH / gridDim.z;
  int kb0 = blockIdx.z * ksl;

  __shared__ int slotbuf[256];
  __shared__ float rwbuf[256];
  __shared__ __align__(16) unsigned short Ash[256 * 64];  // 32 KB
  __shared__ __align__(16) unsigned short Bsh[128 * 64];  // 16 KB

  int t = threadIdx.x;
  if (t < 256) {
    int r = m0 + t;
    int s_ = list[e * BT + (r < cnt_e ? r : 0)];
    slotbuf[t] = s_;
    rwbuf[t] = rw[s_];
  }
  __syncthreads();

  int w = t >> 6, l = t & 63;
  int lm = l & 15, lq = l >> 4;
  int wm = (w & 3) * 64, wn = (w >> 2) * 64;

  const unsigned short* Bsrc = w2t + (size_t)e * OO * HH + (size_t)n0 * HH;

  const unsigned short* aS[4];
  const unsigned short* bS[2];
  unsigned short* aL[4];
  unsigned short* bL[2];
#pragma unroll
  for (int j = 0; j < 4; ++j) {
    int idx = 4 * w + j;                     // 0..31 -> A rows idx*8..+8
    int row = idx * 8 + (l >> 3);
    int koff = (l & 7) * 8;
    aS[j] = hc + (size_t)(base + row) * HH + kb0 + koff;
    aL[j] = &Ash[idx * 512];
  }
#pragma unroll
  for (int j = 0; j < 2; ++j) {
    int idx = 2 * w + j;                     // 0..15 -> B rows idx*8..+8
    int row = idx * 8 + (l >> 3);
    int koff = (l & 7) * 8;
    bS[j] = Bsrc + (size_t)row * HH + kb0 + koff;
    bL[j] = &Bsh[idx * 512];
  }

  f32x4 acc[4][4];
#pragma unroll
  for (int mi = 0; mi < 4; ++mi)
#pragma unroll
    for (int ni = 0; ni < 4; ++ni) acc[mi][ni] = f32x4{0.f, 0.f, 0.f, 0.f};

  for (int k0 = 0; k0 < ksl; k0 += 64) {
#pragma unroll
    for (int j = 0; j < 4; ++j) glds16(aS[j] + k0, aL[j]);
#pragma unroll
    for (int j = 0; j < 2; ++j) glds16(bS[j] + k0, bL[j]);
    __syncthreads();
#pragma unroll
    for (int ks = 0; ks < 2; ++ks) {
      bf16x8 af[4], bfr[4];
      int kb = ks * 32 + lq * 8;
#pragma unroll
      for (int mi = 0; mi < 4; ++mi)
        af[mi] = *(const bf16x8*)&Ash[(wm + mi * 16 + lm) * 64 + kb];
#pragma unroll
      for (int ni = 0; ni < 4; ++ni)
        bfr[ni] = *(const bf16x8*)&Bsh[(wn + ni * 16 + lm) * 64 + kb];
#pragma unroll
      for (int mi = 0; mi < 4; ++mi)
#pragma unroll
        for (int ni = 0; ni < 4; ++ni)
          acc[mi][ni] = __builtin_amdgcn_mfma_f32_16x16x32_bf16(af[mi], bfr[ni], acc[mi][ni], 0, 0, 0);
    }
    __syncthreads();
  }

  bool addbias = (blockIdx.z == 0);
  size_t ybase = (size_t)blockIdx.z * SLOTS;
#pragma unroll
  for (int ni = 0; ni < 4; ++ni) {
    int ncol = n0 + wn + ni * 16 + lm;
    float bias = addbias ? b2[e * OO + ncol] : 0.0f;
#pragma unroll
    for (int mi = 0; mi < 4; ++mi) {
      int mbase = wm + mi * 16 + lq * 4;
#pragma unroll
      for (int r = 0; r < 4; ++r) {
        int mrow = mbase + r;
        if (m0 + mrow < cnt_e) {
          float v = (acc[mi][ni][r] + bias) * rwbuf[mrow];
          int slot = slotbuf[mrow];
          if (ybuf) ybuf[(ybase + slot) * OO + ncol] = v;
          else      atomicAdd(&out[(size_t)(slot >> 1) * OO + ncol], v);
        }
      }
    }
  }
}

// ---- combine: out[b] = sum_z (y[z][2b] + y[z][2b+1]) ----
__global__ __launch_bounds__(256) void combine_k(const float* __restrict__ y,
                                                 float* __restrict__ out, int nz) {
  int i = blockIdx.x * 256 + threadIdx.x;        // one float4 of out
  int b = i >> 8, c = i & 255;                   // 256 float4 per row
  f32x4 acc = {0.f, 0.f, 0.f, 0.f};
  for (int z = 0; z < nz; ++z) {
#pragma unroll
    for (int k = 0; k < 2; ++k) {
      const float4 v = *(const float4*)&y[((size_t)z * SLOTS + 2 * b + k) * OO + c * 4];
      acc[0] += v.x; acc[1] += v.y; acc[2] += v.z; acc[3] += v.w;
    }
  }
  *(f32x4*)&out[(size_t)b * OO + c * 4] = acc;
}

extern "C" void kernel_launch(void* const* d_in, const int* in_sizes, int n_in,
                              void* d_out, int out_size, void* d_ws, size_t ws_size,
                              hipStream_t stream) {
  const float* x  = (const float*)d_in[0];
  const float* gw = (const float*)d_in[1];
  const float* gb = (const float*)d_in[2];
  const float* w1 = (const float*)d_in[3];
  const float* b1 = (const float*)d_in[4];
  const float* w2 = (const float*)d_in[5];
  const float* b2 = (const float*)d_in[6];
  float* out = (float*)d_out;
  char* ws = (char*)d_ws;

  // ws layout
  int*            cnt    = (int*)(ws);                          // 32 B
  int*            ntA    = (int*)(ws + 64);
  int*            ntB    = (int*)(ws + 68);
  int*            tmapA  = (int*)(ws + 128);                    // 72*16 B
  int*            tmapB  = (int*)(ws + 2048);                   // 40*16 B
  float*          rw     = (float*)(ws + 4096);                 // 32 KB
  int*            list   = (int*)(ws + (64u << 10));            // 128 KB
  unsigned short* xb     = (unsigned short*)(ws + (1u  << 20)); // 8 MB
  unsigned short* wt     = (unsigned short*)(ws + (9u  << 20)); // 64 MB (w1t, then w2t)
  unsigned short* hc     = (unsigned short*)(ws + (73u << 20)); // 64 MB + slack
  float*          ybuf   = (float*)(ws + (140u << 20));         // up to 64 MB

  size_t need_min = (140u << 20);
  if (ws_size < need_min) return;
  int zsplit;
  float* ypass;
  if (ws_size >= (140u << 20) + (size_t)2 * SLOTS * OO * 4) { zsplit = 2; ypass = ybuf; }
  else if (ws_size >= (140u << 20) + (size_t)SLOTS * OO * 4) { zsplit = 1; ypass = ybuf; }
  else { zsplit = 2; ypass = nullptr; }

  hipMemsetAsync(cnt, 0, 64, stream);
  if (!ypass) hipMemsetAsync(out, 0, (size_t)BT * OO * sizeof(float), stream);

  router_k<<<BT / 4, 256, 0, stream>>>(x, gw, gb, xb, cnt, list, rw);
  tilemap_k<<<1, 64, 0, stream>>>(cnt, tmapA, ntA, tmapB, ntB);
  cvt_t_k<<<dim3(DD / 64, HH / 64, EE), 256, 0, stream>>>(w1, wt, DD, HH);
  gemm1_k<<<dim3(HH / 128, 72), 256, 0, stream>>>(xb, wt, b1, cnt, list, tmapA, ntA, hc);
  cvt_t_k<<<dim3(HH / 64, OO / 64, EE), 256, 0, stream>>>(w2, wt, HH, OO);
  gemm2_k<<<dim3(OO / 128, 40, zsplit), 512, 0, stream>>>(hc, wt, b2, cnt, list, tmapB, ntB, rw, ypass, out);
  if (ypass)
    combine_k<<<BT * OO / 1024, 256, 0, stream>>>(ybuf, out, zsplit);
}